// Round 6
// baseline (511.267 us; speedup 1.0000x reference)
//
#include <hip/hip_runtime.h>
#include <math.h>

#define NBATCH 4
#define PRE 1024
#define CAND 4096
#define NHIST 65536
#define MAXSLOT 384

typedef __attribute__((address_space(1))) const void GlbVoid;
typedef __attribute__((address_space(3))) void LdsVoid;

__device__ __forceinline__ void gld_lds16(const void* g, void* l) {
    // wave-level DMA: per-lane global src, wave-uniform LDS base + lane*16
    __builtin_amdgcn_global_load_lds((GlbVoid*)g, (LdsVoid*)l, 16, 0, 0);
}

__device__ __forceinline__ unsigned long long allow_mask(int i, int l) {
    // bits j in word l with j > i
    int base = l << 6;
    if (i < base) return ~0ull;
    int sh = i - base + 1;
    if (sh >= 64) return 0ull;
    return (~0ull) << sh;
}

// K0: split weights: f64 for score columns (cls0, cls1, scr), f32 for reg cols 0..7
__global__ void k0_weights(const float* __restrict__ Wcls, const float* __restrict__ bcls,
                           const float* __restrict__ Wreg, const float* __restrict__ breg,
                           double* __restrict__ Wd3, float* __restrict__ Wf8,
                           double* __restrict__ biasD, float* __restrict__ biasF) {
    int j = blockIdx.x;      // 0..10
    int c = threadIdx.x;     // 0..255
    if (j < 2) {
        Wd3[j * 256 + c] = (double)Wcls[c * 2 + j];
        if (c == 0) biasD[j] = (double)bcls[j];
    } else if (j == 10) {
        Wd3[2 * 256 + c] = (double)Wreg[c * 9 + 8];
        if (c == 0) biasD[2] = (double)breg[8];
    } else {
        int r = j - 2;
        Wf8[r * 256 + c] = Wreg[c * 9 + r];
        if (c == 0) biasF[r] = breg[r];
    }
}

// K1: round-1 structure (best measured: 141.7 us full-N), now dispatched as two
// half-N kernels purely for rocprof top-5 visibility of the tail kernels.
// 256 points/block, 8 chunks of 32 channels, 64 KB LDS double buffer staged by
// global_load_lds; swizzled source/read (rule 21).
__global__ __launch_bounds__(256) void k1_points(
    const float* __restrict__ feat, const int* __restrict__ batch_idx,
    const int* __restrict__ coor, const double* __restrict__ Wd3,
    const float* __restrict__ Wf8, const double* __restrict__ biasD,
    const float* __restrict__ biasF, float* __restrict__ pointData,
    unsigned long long* __restrict__ keys, unsigned int* __restrict__ hist,
    int N, int boff) {
    __shared__ float sbuf[2][256 * 32];   // 2 x 32 KiB = 64 KiB
    const int tid = threadIdx.x;
    const int w = tid >> 6, lane = tid & 63;
    const int p0 = (blockIdx.x + boff) * 256;

    double accD0 = 0.0, accD1 = 0.0, accD2 = 0.0;
    float accF[8];
#pragma unroll
    for (int j = 0; j < 8; ++j) accF[j] = 0.f;

    // source column swizzle: row r = w*64 + it*8 + (lane>>3), so (r&7) == (lane>>3);
    // LDS slot (l&7) of row r must hold global float4 (l&7)^(r&7)
    const int s_src = (lane & 7) ^ (lane >> 3);

    auto stage = [&](int buf, int ch) {
#pragma unroll
        for (int it = 0; it < 8; ++it) {
            int R0 = w * 64 + it * 8;            // wave-uniform base row (4 waves cover 256 rows)
            int r = R0 + (lane >> 3);
            int gp = p0 + r;
            if (gp >= N) gp = N - 1;             // clamp: keeps exec uniform, data harmless
            const float* g = feat + (size_t)gp * 256 + ch * 32 + s_src * 4;
            gld_lds16(g, &sbuf[buf][R0 * 32]);   // HW adds lane*16B -> row r, slot lane&7
        }
    };

    auto compute = [&](int buf, int ch) {
        const float* row = &sbuf[buf][tid * 32];
        const int rs = tid & 7;
#pragma unroll
        for (int k4 = 0; k4 < 8; ++k4) {
            const float4 v = *(const float4*)(row + ((k4 ^ rs) * 4));  // un-swizzle
            const int cb = ch * 32 + k4 * 4;
            float vv[4] = {v.x, v.y, v.z, v.w};
#pragma unroll
            for (int m = 0; m < 4; ++m) {
                int c = cb + m;                   // wave-uniform -> scalar weight loads
                double fd = (double)vv[m];
                accD0 = fma(fd, Wd3[c], accD0);
                accD1 = fma(fd, Wd3[256 + c], accD1);
                accD2 = fma(fd, Wd3[512 + c], accD2);
#pragma unroll
                for (int j = 0; j < 8; ++j) accF[j] = fmaf(vv[m], Wf8[j * 256 + c], accF[j]);
            }
        }
    };

    stage(0, 0);
    __syncthreads();                              // drains vmcnt -> chunk 0 ready
    for (int ch = 0; ch < 8; ++ch) {
        if (ch < 7) stage((ch + 1) & 1, ch + 1);  // issue next chunk's DMA under compute
        compute(ch & 1, ch);
        __syncthreads();                          // next chunk ready, buffer reusable
    }

    int gp = p0 + tid;
    if (gp < N) {
        double d0 = biasD[0] + accD0, d1 = biasD[1] + accD1, d2 = biasD[2] + accD2;
        float f[8];
#pragma unroll
        for (int j = 0; j < 8; ++j) f[j] = biasF[j] + accF[j];
        double conf = 1.0 / (1.0 + exp(-(d1 - d0)));   // softmax(2)[1]
        double scr = 1.0 / (1.0 + exp(-d2));
        double score = conf * scr;                      // > 0
        float s32 = (float)score;

        float cx = (float)coor[2 * gp] * 0.8f;
        float cy = (float)coor[2 * gp + 1] * 0.8f;
        float bx = cx + f[0], by = cy + f[1], bz = f[2];
        float bl = expf(fminf(fmaxf(f[3], -6.f), 6.f));
        float bw = expf(fminf(fmaxf(f[4], -6.f), 6.f));
        float bh = expf(fminf(fmaxf(f[5], -6.f), 6.f));
        float ba = atan2f(f[6], f[7]);

        float4* pd = (float4*)(pointData + (size_t)gp * 8);
        pd[0] = make_float4(bx, by, bz, bl);
        pd[1] = make_float4(bw, bh, ba, s32);
        keys[gp] = (unsigned long long)__double_as_longlong(score);
        int b = batch_idx[gp];
        atomicAdd(&hist[b * NHIST + (__float_as_uint(s32) >> 16)], 1u);
    }
}

// K2: per-batch threshold bucket (suffix count >= 1024)
__global__ __launch_bounds__(256) void k2_thresh(const unsigned int* __restrict__ hist,
                                                 unsigned int* __restrict__ Tarr) {
    int b = blockIdx.x, tid = threadIdx.x;
    __shared__ unsigned int csum[256];
    __shared__ unsigned int chunkv[256];
    __shared__ int stc;
    __shared__ unsigned int scum;
    const unsigned int* h = hist + b * NHIST;
    unsigned int s = 0;
    for (int m = 0; m < 256; ++m) s += h[tid * 256 + m];
    csum[tid] = s;
    __syncthreads();
    if (tid == 0) {
        unsigned int cum = 0; int tc = -1;
        for (int t = 255; t >= 0; --t) {
            if (cum + csum[t] >= 1024u) { tc = t; break; }
            cum += csum[t];
        }
        stc = tc; scum = cum;
    }
    __syncthreads();
    int tc = stc;
    if (tc < 0) { if (tid == 0) Tarr[b] = 0u; return; }
    chunkv[tid] = h[tc * 256 + tid];
    __syncthreads();
    if (tid == 0) {
        unsigned int cum = scum, T = (unsigned int)(tc * 256);
        for (int m = 255; m >= 0; --m) {
            unsigned int c = chunkv[m];
            if (cum + c >= 1024u) { T = (unsigned int)(tc * 256 + m); break; }
            cum += c;
        }
        Tarr[b] = T;
    }
}

// K3: compact candidates (bucket >= threshold bucket), wave-aggregated atomics
__global__ void k3_compact(const int* __restrict__ batch_idx, const float* __restrict__ pointData,
                           const unsigned long long* __restrict__ keys,
                           const unsigned int* __restrict__ Tarr, unsigned int* __restrict__ candCount,
                           unsigned int* __restrict__ candIdx, unsigned long long* __restrict__ candKey,
                           int N) {
    int p = blockIdx.x * 256 + threadIdx.x;
    int lane = threadIdx.x & 63;
    bool pred = false;
    int b = 0;
    if (p < N) {
        b = batch_idx[p];
        float s32 = pointData[(size_t)p * 8 + 7];
        unsigned int bucket = __float_as_uint(s32) >> 16;
        pred = (bucket >= Tarr[b]);
    }
#pragma unroll
    for (int bb = 0; bb < NBATCH; ++bb) {
        unsigned long long mk = __ballot(pred && (b == bb));
        if (mk != 0ull) {
            int leader = __ffsll((long long)mk) - 1;
            unsigned int base = 0;
            if (lane == leader) base = atomicAdd(&candCount[bb], (unsigned int)__popcll(mk));
            base = (unsigned int)__shfl((int)base, leader);
            if (pred && (b == bb)) {
                unsigned int pos = base + (unsigned int)__popcll(mk & ((1ull << lane) - 1ull));
                if (pos < CAND) {
                    candIdx[bb * CAND + pos] = (unsigned int)p;
                    candKey[bb * CAND + pos] = keys[p];
                }
            }
        }
    }
}

// K4: per-batch bitonic sort (runtime 2048 or 4096) -> top-1024, gather boxes
__global__ __launch_bounds__(1024) void k4_sort(const unsigned int* __restrict__ candCount,
                                                const unsigned int* __restrict__ candIdx,
                                                const unsigned long long* __restrict__ candKey,
                                                const float* __restrict__ pointData,
                                                float* __restrict__ topBox,
                                                unsigned int* __restrict__ validArr) {
    int b = blockIdx.x, tid = threadIdx.x;
    __shared__ unsigned long long ka[CAND];
    __shared__ unsigned int id[CAND];
    unsigned int cnt = candCount[b];
    if (cnt > CAND) cnt = CAND;
    int n = (cnt <= 2048u) ? 2048 : 4096;
    for (int t = tid; t < n; t += 1024) {
        if ((unsigned int)t < cnt) {
            ka[t] = ~candKey[b * CAND + t];
            id[t] = candIdx[b * CAND + t];
        } else {
            ka[t] = ~0ull;
            id[t] = 0xFFFFFFFFu;
        }
    }
    __syncthreads();
    for (int k = 2; k <= n; k <<= 1) {
        for (int j = k >> 1; j > 0; j >>= 1) {
            for (int t = tid; t < n; t += 1024) {
                int l = t ^ j;
                if (l > t) {
                    bool up = ((t & k) == 0);
                    unsigned long long kt = ka[t], kl = ka[l];
                    unsigned int it_ = id[t], il = id[l];
                    bool gt = (kt > kl) || (kt == kl && it_ > il);
                    if (gt == up) { ka[t] = kl; ka[l] = kt; id[t] = il; id[l] = it_; }
                }
            }
            __syncthreads();
        }
    }
    unsigned int gi = id[tid];
    bool valid = (gi != 0xFFFFFFFFu) && ((unsigned int)tid < cnt);
    float v[8];
#pragma unroll
    for (int k = 0; k < 8; ++k) v[k] = 0.f;
    if (valid) {
        const float* pd = pointData + (size_t)gi * 8;
#pragma unroll
        for (int k = 0; k < 8; ++k) v[k] = pd[k];
    }
    float* tb = topBox + (size_t)(b * PRE + tid) * 8;
#pragma unroll
    for (int k = 0; k < 8; ++k) tb[k] = v[k];
    validArr[b * PRE + tid] = valid ? 1u : 0u;
}

// K5: overlap bit-matrix, upper-triangle words only
__global__ __launch_bounds__(256) void k5_iou(const float* __restrict__ topBox,
                                              unsigned long long* __restrict__ M) {
    int wid = blockIdx.x * 4 + (threadIdx.x >> 6);
    int lane = threadIdx.x & 63;
    int b = wid >> 14;
    int rem = wid & 16383;
    int i = rem >> 4;
    int wj = rem & 15;
    if (wj < (i >> 6)) return;               // wave-uniform; k6 masks these words
    const float* bi = topBox + (size_t)(b * PRE + i) * 8;
    int j = wj * 64 + lane;
    const float* bj = topBox + (size_t)(b * PRE + j) * 8;
    float xi = bi[0], yi = bi[1], li = bi[3], wi_ = bi[4];
    float xj = bj[0], yj = bj[1], lj = bj[3], wj_ = bj[4];
    float x1i = xi - li * 0.5f, x2i = xi + li * 0.5f;
    float y1i = yi - wi_ * 0.5f, y2i = yi + wi_ * 0.5f;
    float x1j = xj - lj * 0.5f, x2j = xj + lj * 0.5f;
    float y1j = yj - wj_ * 0.5f, y2j = yj + wj_ * 0.5f;
    float ix = fmaxf(fminf(x2i, x2j) - fmaxf(x1i, x1j), 0.0f);
    float iy = fmaxf(fminf(y2i, y2j) - fmaxf(y1i, y1j), 0.0f);
    float inter = ix * iy;
    float ai = li * wi_, aj = lj * wj_;
    float uni = ai + aj - inter;
    float iou = inter / fmaxf(uni, 1e-6f);
    unsigned long long m = __ballot(iou > 0.1f);
    if (lane == 0) M[(size_t)(b * PRE + i) * 16 + wj] = m;
}

// K6: compact flagged rows into LDS, sparse greedy NMS, write outputs
__global__ __launch_bounds__(256) void k6_nms(const unsigned long long* __restrict__ M,
                                              const unsigned int* __restrict__ validArr,
                                              const float* __restrict__ topBox,
                                              float* __restrict__ out0,
                                              float* __restrict__ keepOut) {
    __shared__ unsigned long long Mc[MAXSLOT * 16];   // 48 KB
    __shared__ unsigned int slotIdx[PRE];
    __shared__ unsigned int cntSh;
    __shared__ unsigned long long suppSh[16];
    int b = blockIdx.x, tid = threadIdx.x;
    if (tid == 0) cntSh = 0;
    __syncthreads();
    for (int r = tid; r < PRE; r += 256) {
        const unsigned long long* row = M + (size_t)(b * PRE + r) * 16;
        unsigned long long w[16];
        unsigned long long o = 0ull;
#pragma unroll
        for (int l = 0; l < 16; ++l) { w[l] = row[l] & allow_mask(r, l); o |= w[l]; }
        unsigned int s = 0xFFFFFFFFu;
        if (o != 0ull) {
            unsigned int slot = atomicAdd(&cntSh, 1u);
            if (slot < MAXSLOT) {
                s = slot;
#pragma unroll
                for (int l = 0; l < 16; ++l) Mc[slot * 16 + l] = w[l];
            } else s = 0xFFFFFFFEu;
        }
        slotIdx[r] = s;
    }
    __syncthreads();
    if (tid < 64) {
        int lane = tid;
        unsigned long long supp = 0ull;                // word `lane` (lane<16)
        for (int g = 0; g < 16; ++g) {
            unsigned long long act = __ballot(slotIdx[g * 64 + lane] != 0xFFFFFFFFu);
            while (act) {
                int bit = __builtin_ctzll(act);
                act &= act - 1ull;
                int i = g * 64 + bit;
                unsigned long long wsup = __shfl(supp, g);
                bool keep_i = ((wsup >> (i & 63)) & 1ull) == 0ull;
                if (keep_i && lane < 16) {
                    unsigned int s = slotIdx[i];
                    unsigned long long add = (s < MAXSLOT)
                        ? Mc[s * 16 + lane]
                        : (M[(size_t)(b * PRE + i) * 16 + lane] & allow_mask(i, lane));
                    supp |= add;
                }
            }
        }
        if (lane < 16) suppSh[lane] = supp;
    }
    __syncthreads();
    for (int r = tid; r < PRE; r += 256) {
        bool keep = (((suppSh[r >> 6] >> (r & 63)) & 1ull) == 0ull) && (validArr[b * PRE + r] != 0u);
        float kf = keep ? 1.0f : 0.0f;
        const float* tb = topBox + (size_t)(b * PRE + r) * 8;
        float* o = out0 + (size_t)(b * PRE + r) * 8;
#pragma unroll
        for (int k = 0; k < 8; ++k) o[k] = tb[k] * kf;
        keepOut[b * PRE + r] = kf;
    }
}

extern "C" void kernel_launch(void* const* d_in, const int* in_sizes, int n_in,
                              void* d_out, int out_size, void* d_ws, size_t ws_size,
                              hipStream_t stream) {
    int N = in_sizes[0] / 256;
    const float* feat = (const float*)d_in[0];
    const int* batch_idx = (const int*)d_in[1];
    const int* coor = (const int*)d_in[2];
    const float* Wcls = (const float*)d_in[3];
    const float* bcls = (const float*)d_in[4];
    const float* Wreg = (const float*)d_in[5];
    const float* breg = (const float*)d_in[6];

    char* ws = (char*)d_ws;
    size_t off = 0;
    auto take = [&](size_t bytes) -> char* {
        char* r = ws + off;
        off += (bytes + 255) & ~(size_t)255;
        return r;
    };
    float* pointData = (float*)take((size_t)N * 8 * 4);
    unsigned long long* keys = (unsigned long long*)take((size_t)N * 8);
    unsigned int* hist = (unsigned int*)take((size_t)NBATCH * NHIST * 4);   // hist..candCount
    unsigned int* candCount = (unsigned int*)take(NBATCH * 4);              //   zeroed together
    unsigned int* Tarr = (unsigned int*)take(NBATCH * 4);
    unsigned int* candIdx = (unsigned int*)take(NBATCH * CAND * 4);
    unsigned long long* candKey = (unsigned long long*)take(NBATCH * CAND * 8);
    float* topBox = (float*)take(NBATCH * PRE * 8 * 4);
    unsigned int* validArr = (unsigned int*)take(NBATCH * PRE * 4);
    unsigned long long* M = (unsigned long long*)take((size_t)NBATCH * PRE * 16 * 8);
    double* Wd3 = (double*)take(3 * 256 * 8);
    float* Wf8 = (float*)take(8 * 256 * 4);
    double* biasD = (double*)take(3 * 8);
    float* biasF = (float*)take(8 * 4);

    float* out0 = (float*)d_out;                              // (4,1024,8)
    float* keepOut = out0 + NBATCH * PRE * 8 + NBATCH * PRE;  // after lb (all-zero)

    hipMemsetAsync(d_out, 0, (size_t)out_size * 4, stream);
    hipMemsetAsync(hist, 0, (size_t)NBATCH * NHIST * 4 + NBATCH * 4, stream);

    int nb = (N + 255) / 256;
    int nb1 = nb / 2;               // k1 split in two for tail visibility in top-5
    int nb2 = nb - nb1;
    k0_weights<<<dim3(11), dim3(256), 0, stream>>>(Wcls, bcls, Wreg, breg, Wd3, Wf8, biasD, biasF);
    k1_points<<<dim3(nb1), dim3(256), 0, stream>>>(feat, batch_idx, coor,
                                                   Wd3, Wf8, biasD, biasF,
                                                   pointData, keys, hist, N, 0);
    k1_points<<<dim3(nb2), dim3(256), 0, stream>>>(feat, batch_idx, coor,
                                                   Wd3, Wf8, biasD, biasF,
                                                   pointData, keys, hist, N, nb1);
    k2_thresh<<<dim3(NBATCH), dim3(256), 0, stream>>>(hist, Tarr);
    k3_compact<<<dim3(nb), dim3(256), 0, stream>>>(batch_idx, pointData, keys, Tarr,
                                                   candCount, candIdx, candKey, N);
    k4_sort<<<dim3(NBATCH), dim3(1024), 0, stream>>>(candCount, candIdx, candKey,
                                                     pointData, topBox, validArr);
    k5_iou<<<dim3(NBATCH * PRE * 16 / 4), dim3(256), 0, stream>>>(topBox, M);
    k6_nms<<<dim3(NBATCH), dim3(256), 0, stream>>>(M, validArr, topBox, out0, keepOut);
}

// Round 7
// 457.453 us; speedup vs baseline: 1.1176x; 1.1176x over previous
//
#include <hip/hip_runtime.h>
#include <math.h>

#define NBATCH 4
#define PRE 1024
#define CAND 4096
#define NHIST 65536
#define MAXSLOT 384

typedef __attribute__((address_space(1))) const void GlbVoid;
typedef __attribute__((address_space(3))) void LdsVoid;

__device__ __forceinline__ void gld_lds16(const void* g, void* l) {
    // wave-level DMA: per-lane global src, wave-uniform LDS base + lane*16
    __builtin_amdgcn_global_load_lds((GlbVoid*)g, (LdsVoid*)l, 16, 0, 0);
}

__device__ __forceinline__ unsigned long long allow_mask(int i, int l) {
    // bits j in word l with j > i
    int base = l << 6;
    if (i < base) return ~0ull;
    int sh = i - base + 1;
    if (sh >= 64) return 0ull;
    return (~0ull) << sh;
}

// K0: split weights: f64 for score columns (cls0, cls1, scr), f32 for reg cols 0..7
__global__ void k0_weights(const float* __restrict__ Wcls, const float* __restrict__ bcls,
                           const float* __restrict__ Wreg, const float* __restrict__ breg,
                           double* __restrict__ Wd3, float* __restrict__ Wf8,
                           double* __restrict__ biasD, float* __restrict__ biasF) {
    int j = blockIdx.x;      // 0..10
    int c = threadIdx.x;     // 0..255
    if (j < 2) {
        Wd3[j * 256 + c] = (double)Wcls[c * 2 + j];
        if (c == 0) biasD[j] = (double)bcls[j];
    } else if (j == 10) {
        Wd3[2 * 256 + c] = (double)Wreg[c * 9 + 8];
        if (c == 0) biasD[2] = (double)breg[8];
    } else {
        int r = j - 2;
        Wf8[r * 256 + c] = Wreg[c * 9 + r];
        if (c == 0) biasF[r] = breg[r];
    }
}

// K1: round-1 structure (best measured: 141.7 us). 256 points/block, 8 chunks of
// 32 channels, 64 KB LDS double buffer staged by global_load_lds; swizzled
// source/read (rule 21). Only change vs round 1: no keys[] store (k4 now packs
// the sort key from the f32 score).
__global__ __launch_bounds__(256) void k1_points(
    const float* __restrict__ feat, const int* __restrict__ batch_idx,
    const int* __restrict__ coor, const double* __restrict__ Wd3,
    const float* __restrict__ Wf8, const double* __restrict__ biasD,
    const float* __restrict__ biasF, float* __restrict__ pointData,
    unsigned int* __restrict__ hist, int N) {
    __shared__ float sbuf[2][256 * 32];   // 2 x 32 KiB = 64 KiB
    const int tid = threadIdx.x;
    const int w = tid >> 6, lane = tid & 63;
    const int p0 = blockIdx.x * 256;

    double accD0 = 0.0, accD1 = 0.0, accD2 = 0.0;
    float accF[8];
#pragma unroll
    for (int j = 0; j < 8; ++j) accF[j] = 0.f;

    // source column swizzle: row r = w*64 + it*8 + (lane>>3), so (r&7) == (lane>>3);
    // LDS slot (l&7) of row r must hold global float4 (l&7)^(r&7)
    const int s_src = (lane & 7) ^ (lane >> 3);

    auto stage = [&](int buf, int ch) {
#pragma unroll
        for (int it = 0; it < 8; ++it) {
            int R0 = w * 64 + it * 8;            // wave-uniform base row (4 waves cover 256 rows)
            int r = R0 + (lane >> 3);
            int gp = p0 + r;
            if (gp >= N) gp = N - 1;             // clamp: keeps exec uniform, data harmless
            const float* g = feat + (size_t)gp * 256 + ch * 32 + s_src * 4;
            gld_lds16(g, &sbuf[buf][R0 * 32]);   // HW adds lane*16B -> row r, slot lane&7
        }
    };

    auto compute = [&](int buf, int ch) {
        const float* row = &sbuf[buf][tid * 32];
        const int rs = tid & 7;
#pragma unroll
        for (int k4 = 0; k4 < 8; ++k4) {
            const float4 v = *(const float4*)(row + ((k4 ^ rs) * 4));  // un-swizzle
            const int cb = ch * 32 + k4 * 4;
            float vv[4] = {v.x, v.y, v.z, v.w};
#pragma unroll
            for (int m = 0; m < 4; ++m) {
                int c = cb + m;                   // wave-uniform -> scalar weight loads
                double fd = (double)vv[m];
                accD0 = fma(fd, Wd3[c], accD0);
                accD1 = fma(fd, Wd3[256 + c], accD1);
                accD2 = fma(fd, Wd3[512 + c], accD2);
#pragma unroll
                for (int j = 0; j < 8; ++j) accF[j] = fmaf(vv[m], Wf8[j * 256 + c], accF[j]);
            }
        }
    };

    stage(0, 0);
    __syncthreads();                              // drains vmcnt -> chunk 0 ready
    for (int ch = 0; ch < 8; ++ch) {
        if (ch < 7) stage((ch + 1) & 1, ch + 1);  // issue next chunk's DMA under compute
        compute(ch & 1, ch);
        __syncthreads();                          // next chunk ready, buffer reusable
    }

    int gp = p0 + tid;
    if (gp < N) {
        double d0 = biasD[0] + accD0, d1 = biasD[1] + accD1, d2 = biasD[2] + accD2;
        float f[8];
#pragma unroll
        for (int j = 0; j < 8; ++j) f[j] = biasF[j] + accF[j];
        double conf = 1.0 / (1.0 + exp(-(d1 - d0)));   // softmax(2)[1]
        double scr = 1.0 / (1.0 + exp(-d2));
        double score = conf * scr;                      // > 0
        float s32 = (float)score;

        float cx = (float)coor[2 * gp] * 0.8f;
        float cy = (float)coor[2 * gp + 1] * 0.8f;
        float bx = cx + f[0], by = cy + f[1], bz = f[2];
        float bl = expf(fminf(fmaxf(f[3], -6.f), 6.f));
        float bw = expf(fminf(fmaxf(f[4], -6.f), 6.f));
        float bh = expf(fminf(fmaxf(f[5], -6.f), 6.f));
        float ba = atan2f(f[6], f[7]);

        float4* pd = (float4*)(pointData + (size_t)gp * 8);
        pd[0] = make_float4(bx, by, bz, bl);
        pd[1] = make_float4(bw, bh, ba, s32);
        int b = batch_idx[gp];
        atomicAdd(&hist[b * NHIST + (__float_as_uint(s32) >> 16)], 1u);
    }
}

// K2: per-batch threshold bucket (suffix count >= 1024)
__global__ __launch_bounds__(256) void k2_thresh(const unsigned int* __restrict__ hist,
                                                 unsigned int* __restrict__ Tarr) {
    int b = blockIdx.x, tid = threadIdx.x;
    __shared__ unsigned int csum[256];
    __shared__ unsigned int chunkv[256];
    __shared__ int stc;
    __shared__ unsigned int scum;
    const unsigned int* h = hist + b * NHIST;
    unsigned int s = 0;
    for (int m = 0; m < 256; ++m) s += h[tid * 256 + m];
    csum[tid] = s;
    __syncthreads();
    if (tid == 0) {
        unsigned int cum = 0; int tc = -1;
        for (int t = 255; t >= 0; --t) {
            if (cum + csum[t] >= 1024u) { tc = t; break; }
            cum += csum[t];
        }
        stc = tc; scum = cum;
    }
    __syncthreads();
    int tc = stc;
    if (tc < 0) { if (tid == 0) Tarr[b] = 0u; return; }
    chunkv[tid] = h[tc * 256 + tid];
    __syncthreads();
    if (tid == 0) {
        unsigned int cum = scum, T = (unsigned int)(tc * 256);
        for (int m = 255; m >= 0; --m) {
            unsigned int c = chunkv[m];
            if (cum + c >= 1024u) { T = (unsigned int)(tc * 256 + m); break; }
            cum += c;
        }
        Tarr[b] = T;
    }
}

// K3: compact candidates (bucket >= threshold bucket); writes PACKED sort key:
// (~f32_score_bits)<<32 | idx  -> ascending u64 = descending score, tie -> low idx
// (matches lax.top_k stability on the f32 score).
__global__ void k3_compact(const int* __restrict__ batch_idx, const float* __restrict__ pointData,
                           const unsigned int* __restrict__ Tarr, unsigned int* __restrict__ candCount,
                           unsigned long long* __restrict__ candKey, int N) {
    int p = blockIdx.x * 256 + threadIdx.x;
    if (p >= N) return;
    int b = batch_idx[p];
    float s32 = pointData[(size_t)p * 8 + 7];
    unsigned int sb = __float_as_uint(s32);
    if ((sb >> 16) >= Tarr[b]) {
        unsigned int pos = atomicAdd(&candCount[b], 1u);
        if (pos < CAND) {
            candKey[b * CAND + pos] = ((unsigned long long)(~sb) << 32) | (unsigned int)p;
        }
    }
}

// K4: per-batch bitonic sort of packed u64 keys (payload = low 32 bits) ->
// top-1024, gather boxes. Half the LDS traffic of the old key+id sort.
__global__ __launch_bounds__(1024) void k4_sort(const unsigned int* __restrict__ candCount,
                                                const unsigned long long* __restrict__ candKey,
                                                const float* __restrict__ pointData,
                                                float* __restrict__ topBox,
                                                unsigned int* __restrict__ validArr) {
    int b = blockIdx.x, tid = threadIdx.x;
    __shared__ unsigned long long ka[CAND];   // 32 KB
    unsigned int cnt = candCount[b];
    if (cnt > CAND) cnt = CAND;
    int n = (cnt <= 2048u) ? 2048 : 4096;
    for (int t = tid; t < n; t += 1024)
        ka[t] = ((unsigned int)t < cnt) ? candKey[b * CAND + t] : ~0ull;
    __syncthreads();
    for (int k = 2; k <= n; k <<= 1) {
        for (int j = k >> 1; j > 0; j >>= 1) {
            for (int t = tid; t < n; t += 1024) {
                int l = t ^ j;
                if (l > t) {
                    bool up = ((t & k) == 0);
                    unsigned long long kt = ka[t], kl = ka[l];
                    if ((kt > kl) == up) { ka[t] = kl; ka[l] = kt; }
                }
            }
            __syncthreads();
        }
    }
    unsigned long long kt = ka[tid];
    unsigned int gi = (unsigned int)kt;
    bool valid = ((unsigned int)tid < cnt) && (gi != 0xFFFFFFFFu);
    float v[8];
#pragma unroll
    for (int k = 0; k < 8; ++k) v[k] = 0.f;
    if (valid) {
        const float* pd = pointData + (size_t)gi * 8;
#pragma unroll
        for (int k = 0; k < 8; ++k) v[k] = pd[k];
    }
    float* tb = topBox + (size_t)(b * PRE + tid) * 8;
#pragma unroll
    for (int k = 0; k < 8; ++k) tb[k] = v[k];
    validArr[b * PRE + tid] = valid ? 1u : 0u;
}

// K5: overlap bit-matrix, upper-triangle words only
__global__ __launch_bounds__(256) void k5_iou(const float* __restrict__ topBox,
                                              unsigned long long* __restrict__ M) {
    int wid = blockIdx.x * 4 + (threadIdx.x >> 6);
    int lane = threadIdx.x & 63;
    int b = wid >> 14;
    int rem = wid & 16383;
    int i = rem >> 4;
    int wj = rem & 15;
    if (wj < (i >> 6)) return;               // wave-uniform; k6 masks these words
    const float* bi = topBox + (size_t)(b * PRE + i) * 8;
    int j = wj * 64 + lane;
    const float* bj = topBox + (size_t)(b * PRE + j) * 8;
    float xi = bi[0], yi = bi[1], li = bi[3], wi_ = bi[4];
    float xj = bj[0], yj = bj[1], lj = bj[3], wj_ = bj[4];
    float x1i = xi - li * 0.5f, x2i = xi + li * 0.5f;
    float y1i = yi - wi_ * 0.5f, y2i = yi + wi_ * 0.5f;
    float x1j = xj - lj * 0.5f, x2j = xj + lj * 0.5f;
    float y1j = yj - wj_ * 0.5f, y2j = yj + wj_ * 0.5f;
    float ix = fmaxf(fminf(x2i, x2j) - fmaxf(x1i, x1j), 0.0f);
    float iy = fmaxf(fminf(y2i, y2j) - fmaxf(y1i, y1j), 0.0f);
    float inter = ix * iy;
    float ai = li * wi_, aj = lj * wj_;
    float uni = ai + aj - inter;
    float iou = inter / fmaxf(uni, 1e-6f);
    unsigned long long m = __ballot(iou > 0.1f);
    if (lane == 0) M[(size_t)(b * PRE + i) * 16 + wj] = m;
}

// K6: compact flagged rows into LDS, sparse greedy NMS, write outputs
__global__ __launch_bounds__(256) void k6_nms(const unsigned long long* __restrict__ M,
                                              const unsigned int* __restrict__ validArr,
                                              const float* __restrict__ topBox,
                                              float* __restrict__ out0,
                                              float* __restrict__ keepOut) {
    __shared__ unsigned long long Mc[MAXSLOT * 16];   // 48 KB
    __shared__ unsigned int slotIdx[PRE];
    __shared__ unsigned int cntSh;
    __shared__ unsigned long long suppSh[16];
    int b = blockIdx.x, tid = threadIdx.x;
    if (tid == 0) cntSh = 0;
    __syncthreads();
    for (int r = tid; r < PRE; r += 256) {
        const unsigned long long* row = M + (size_t)(b * PRE + r) * 16;
        unsigned long long w[16];
        unsigned long long o = 0ull;
#pragma unroll
        for (int l = 0; l < 16; ++l) { w[l] = row[l] & allow_mask(r, l); o |= w[l]; }
        unsigned int s = 0xFFFFFFFFu;
        if (o != 0ull) {
            unsigned int slot = atomicAdd(&cntSh, 1u);
            if (slot < MAXSLOT) {
                s = slot;
#pragma unroll
                for (int l = 0; l < 16; ++l) Mc[slot * 16 + l] = w[l];
            } else s = 0xFFFFFFFEu;
        }
        slotIdx[r] = s;
    }
    __syncthreads();
    if (tid < 64) {
        int lane = tid;
        unsigned long long supp = 0ull;                // word `lane` (lane<16)
        for (int g = 0; g < 16; ++g) {
            unsigned long long act = __ballot(slotIdx[g * 64 + lane] != 0xFFFFFFFFu);
            while (act) {
                int bit = __builtin_ctzll(act);
                act &= act - 1ull;
                int i = g * 64 + bit;
                unsigned long long wsup = __shfl(supp, g);
                bool keep_i = ((wsup >> (i & 63)) & 1ull) == 0ull;
                if (keep_i && lane < 16) {
                    unsigned int s = slotIdx[i];
                    unsigned long long add = (s < MAXSLOT)
                        ? Mc[s * 16 + lane]
                        : (M[(size_t)(b * PRE + i) * 16 + lane] & allow_mask(i, lane));
                    supp |= add;
                }
            }
        }
        if (lane < 16) suppSh[lane] = supp;
    }
    __syncthreads();
    for (int r = tid; r < PRE; r += 256) {
        bool keep = (((suppSh[r >> 6] >> (r & 63)) & 1ull) == 0ull) && (validArr[b * PRE + r] != 0u);
        float kf = keep ? 1.0f : 0.0f;
        const float* tb = topBox + (size_t)(b * PRE + r) * 8;
        float* o = out0 + (size_t)(b * PRE + r) * 8;
#pragma unroll
        for (int k = 0; k < 8; ++k) o[k] = tb[k] * kf;
        keepOut[b * PRE + r] = kf;
    }
}

extern "C" void kernel_launch(void* const* d_in, const int* in_sizes, int n_in,
                              void* d_out, int out_size, void* d_ws, size_t ws_size,
                              hipStream_t stream) {
    int N = in_sizes[0] / 256;
    const float* feat = (const float*)d_in[0];
    const int* batch_idx = (const int*)d_in[1];
    const int* coor = (const int*)d_in[2];
    const float* Wcls = (const float*)d_in[3];
    const float* bcls = (const float*)d_in[4];
    const float* Wreg = (const float*)d_in[5];
    const float* breg = (const float*)d_in[6];

    char* ws = (char*)d_ws;
    size_t off = 0;
    auto take = [&](size_t bytes) -> char* {
        char* r = ws + off;
        off += (bytes + 255) & ~(size_t)255;
        return r;
    };
    float* pointData = (float*)take((size_t)N * 8 * 4);
    unsigned int* hist = (unsigned int*)take((size_t)NBATCH * NHIST * 4);   // hist..candCount
    unsigned int* candCount = (unsigned int*)take(NBATCH * 4);              //   zeroed together
    unsigned int* Tarr = (unsigned int*)take(NBATCH * 4);
    unsigned long long* candKey = (unsigned long long*)take(NBATCH * CAND * 8);
    float* topBox = (float*)take(NBATCH * PRE * 8 * 4);
    unsigned int* validArr = (unsigned int*)take(NBATCH * PRE * 4);
    unsigned long long* M = (unsigned long long*)take((size_t)NBATCH * PRE * 16 * 8);
    double* Wd3 = (double*)take(3 * 256 * 8);
    float* Wf8 = (float*)take(8 * 256 * 4);
    double* biasD = (double*)take(3 * 8);
    float* biasF = (float*)take(8 * 4);

    float* out0 = (float*)d_out;                              // (4,1024,8)
    float* keepOut = out0 + NBATCH * PRE * 8 + NBATCH * PRE;  // after lb (all-zero)

    hipMemsetAsync(d_out, 0, (size_t)out_size * 4, stream);
    hipMemsetAsync(hist, 0, (size_t)NBATCH * NHIST * 4 + NBATCH * 4, stream);

    int pbPts = (N + 255) / 256;
    k0_weights<<<dim3(11), dim3(256), 0, stream>>>(Wcls, bcls, Wreg, breg, Wd3, Wf8, biasD, biasF);
    k1_points<<<dim3(pbPts), dim3(256), 0, stream>>>(feat, batch_idx, coor,
                                                     Wd3, Wf8, biasD, biasF,
                                                     pointData, hist, N);
    k2_thresh<<<dim3(NBATCH), dim3(256), 0, stream>>>(hist, Tarr);
    k3_compact<<<dim3(pbPts), dim3(256), 0, stream>>>(batch_idx, pointData, Tarr,
                                                      candCount, candKey, N);
    k4_sort<<<dim3(NBATCH), dim3(1024), 0, stream>>>(candCount, candKey,
                                                     pointData, topBox, validArr);
    k5_iou<<<dim3(NBATCH * PRE * 16 / 4), dim3(256), 0, stream>>>(topBox, M);
    k6_nms<<<dim3(NBATCH), dim3(256), 0, stream>>>(M, validArr, topBox, out0, keepOut);
}